// Round 1
// baseline (181.680 us; speedup 1.0000x reference)
//
#include <hip/hip_runtime.h>
#include <stdint.h>

typedef float  f32x4 __attribute__((ext_vector_type(4)));
typedef short  s16x8 __attribute__((ext_vector_type(8)));
typedef unsigned short u16;
typedef unsigned short u16x4 __attribute__((ext_vector_type(4)));

#define HID 768
#define OUTF 128
#define LQ 32
#define LD 256
#define BD 512

// f32 -> bf16 round-to-nearest-even (inputs are finite)
__device__ __forceinline__ u16 f2bf(float x) {
    unsigned u = __builtin_bit_cast(unsigned, x);
    u += 0x7fffu + ((u >> 16) & 1u);
    return (u16)(u >> 16);
}

__device__ __forceinline__ s16x8 cvt8(f32x4 a, f32x4 b) {
    s16x8 r;
    r[0] = (short)f2bf(a[0]); r[1] = (short)f2bf(a[1]);
    r[2] = (short)f2bf(a[2]); r[3] = (short)f2bf(a[3]);
    r[4] = (short)f2bf(b[0]); r[5] = (short)f2bf(b[1]);
    r[6] = (short)f2bf(b[2]); r[7] = (short)f2bf(b[3]);
    return r;
}

// ---------------- kernel 0: W f32 -> bf16 ----------------
__global__ __launch_bounds__(256) void wconv(const float* __restrict__ W,
                                             u16* __restrict__ Wb) {
    int i = (blockIdx.x * 256 + threadIdx.x) * 4;   // grid covers exactly 128*768
    f32x4 v = *(const f32x4*)(W + i);
    u16x4 o;
    o[0] = f2bf(v[0]); o[1] = f2bf(v[1]); o[2] = f2bf(v[2]); o[3] = f2bf(v[3]);
    *(u16x4*)(Wb + i) = o;
}

// ---------------- kernel 1: Q projection + L2 norm -> bf16 ----------------
// grid = 64 (one b each), block = 256 (4 waves, wave w owns cols [32w,32w+32))
__global__ __launch_bounds__(256) void qproj(const float* __restrict__ qh,
                                             const u16* __restrict__ Wb,
                                             u16* __restrict__ Qb) {
    const int b = blockIdx.x;
    const int tid = threadIdx.x;
    const int w = tid >> 6, lane = tid & 63, g = lane >> 4, l15 = lane & 15;

    f32x4 acc[2][2] = {};
    const float* A = qh + (size_t)b * LQ * HID;

    for (int k = 0; k < HID; k += 32) {
        s16x8 a[2], bb[2];
#pragma unroll
        for (int rf = 0; rf < 2; ++rf) {
            const float* ap = A + (size_t)(rf * 16 + l15) * HID + k + g * 8;
            a[rf] = cvt8(*(const f32x4*)ap, *(const f32x4*)(ap + 4));
        }
#pragma unroll
        for (int cf = 0; cf < 2; ++cf)
            bb[cf] = *(const s16x8*)(Wb + (size_t)(w * 32 + cf * 16 + l15) * HID + k + g * 8);
#pragma unroll
        for (int rf = 0; rf < 2; ++rf)
#pragma unroll
            for (int cf = 0; cf < 2; ++cf)
                acc[rf][cf] = __builtin_amdgcn_mfma_f32_16x16x32_bf16(a[rf], bb[cf], acc[rf][cf], 0, 0, 0);
    }

    __shared__ float part[4][32];
    __shared__ float invl[32];
#pragma unroll
    for (int rf = 0; rf < 2; ++rf)
#pragma unroll
        for (int reg = 0; reg < 4; ++reg) {
            float ss = acc[rf][0][reg] * acc[rf][0][reg] + acc[rf][1][reg] * acc[rf][1][reg];
            ss += __shfl_xor(ss, 1); ss += __shfl_xor(ss, 2);
            ss += __shfl_xor(ss, 4); ss += __shfl_xor(ss, 8);
            if (l15 == 0) part[w][rf * 16 + g * 4 + reg] = ss;
        }
    __syncthreads();
    if (tid < 32) {
        float ss = part[0][tid] + part[1][tid] + part[2][tid] + part[3][tid];
        invl[tid] = 1.f / fmaxf(sqrtf(ss), 1e-12f);
    }
    __syncthreads();
#pragma unroll
    for (int rf = 0; rf < 2; ++rf)
#pragma unroll
        for (int cf = 0; cf < 2; ++cf)
#pragma unroll
            for (int reg = 0; reg < 4; ++reg) {
                int q = rf * 16 + g * 4 + reg;
                int f = w * 32 + cf * 16 + l15;
                Qb[(size_t)b * LQ * OUTF + q * OUTF + f] = f2bf(acc[rf][cf][reg] * invl[q]);
            }
}

// ---------------- kernel 2: D projection + norm + mask + MaxSim ----------------
// grid = 512 (one doc each), block = 512 (8 waves; wave w owns doc rows [32w,32w+32))
__global__ __launch_bounds__(512, 4) void dscore(const float* __restrict__ dh,
                                                 const int* __restrict__ ids,
                                                 const int* __restrict__ skiplist,
                                                 const u16* __restrict__ Wb,
                                                 const u16* __restrict__ Qb,
                                                 float* __restrict__ out) {
    const int bd = blockIdx.x;
    const int tid = threadIdx.x;
    const int w = tid >> 6, lane = tid & 63, g = lane >> 4, l15 = lane & 15;

    __shared__ u16  Dls[8 * 32 * OUTF];   // 64 KB, XOR-swizzled rows
    __shared__ int  ms[LD];
    __shared__ int  sk[64];
    __shared__ float wm[8][32];

    // ----- mask -----
    if (tid < 64) sk[tid] = skiplist[tid];
    __syncthreads();
    if (tid < LD) {
        int id = ids[(size_t)bd * LD + tid];
        int keep = (id != 0);
#pragma unroll
        for (int j = 0; j < 64; ++j) keep &= (id != sk[j]);
        ms[tid] = keep;
    }
    __syncthreads();

    // ----- projection GEMM: rows [32w,32w+32) x cols 128, K=768 -----
    f32x4 acc[2][8] = {};
    const float* A = dh + (size_t)bd * LD * HID;
    const int rowbase = w * 32;

    for (int k = 0; k < HID; k += 32) {
        s16x8 a[2];
#pragma unroll
        for (int rf = 0; rf < 2; ++rf) {
            const float* ap = A + (size_t)(rowbase + rf * 16 + l15) * HID + k + g * 8;
            a[rf] = cvt8(*(const f32x4*)ap, *(const f32x4*)(ap + 4));
        }
#pragma unroll
        for (int cf = 0; cf < 8; ++cf) {
            s16x8 bf = *(const s16x8*)(Wb + (size_t)(cf * 16 + l15) * HID + k + g * 8);
            acc[0][cf] = __builtin_amdgcn_mfma_f32_16x16x32_bf16(a[0], bf, acc[0][cf], 0, 0, 0);
            acc[1][cf] = __builtin_amdgcn_mfma_f32_16x16x32_bf16(a[1], bf, acc[1][cf], 0, 0, 0);
        }
    }

    // ----- per-row L2 norm (cols spread over l15 groups) -----
    float inv[2][4];
#pragma unroll
    for (int rf = 0; rf < 2; ++rf)
#pragma unroll
        for (int reg = 0; reg < 4; ++reg) {
            float ss = 0.f;
#pragma unroll
            for (int cf = 0; cf < 8; ++cf) ss += acc[rf][cf][reg] * acc[rf][cf][reg];
            ss += __shfl_xor(ss, 1); ss += __shfl_xor(ss, 2);
            ss += __shfl_xor(ss, 4); ss += __shfl_xor(ss, 8);
            inv[rf][reg] = 1.f / fmaxf(sqrtf(ss), 1e-12f);
        }

    // ----- write normalized D (bf16) to swizzled LDS (own wave slice only) -----
#pragma unroll
    for (int rf = 0; rf < 2; ++rf)
#pragma unroll
        for (int cf = 0; cf < 8; ++cf)
#pragma unroll
            for (int reg = 0; reg < 4; ++reg) {
                int r = rowbase + rf * 16 + g * 4 + reg;   // 0..255 block-local
                int f = cf * 16 + l15;
                Dls[(r * OUTF + f) ^ ((r & 7) << 3)] = f2bf(acc[rf][cf][reg] * inv[rf][reg]);
            }

    // ----- sim = Q[b] (32xK=128) x D_wave^T (32 rows), per-wave, K=128 -----
    f32x4 acc2[2][2] = {};
    const u16* Qbb = Qb + (size_t)(bd >> 3) * LQ * OUTF;
    for (int k = 0; k < OUTF; k += 32) {
        s16x8 qa[2], db[2];
#pragma unroll
        for (int qf = 0; qf < 2; ++qf)
            qa[qf] = *(const s16x8*)(Qbb + (qf * 16 + l15) * OUTF + k + g * 8);
#pragma unroll
        for (int nf = 0; nf < 2; ++nf) {
            int r = rowbase + nf * 16 + l15;
            db[nf] = *(const s16x8*)&Dls[(r * OUTF + k + g * 8) ^ ((r & 7) << 3)];
        }
#pragma unroll
        for (int qf = 0; qf < 2; ++qf)
#pragma unroll
            for (int nf = 0; nf < 2; ++nf)
                acc2[qf][nf] = __builtin_amdgcn_mfma_f32_16x16x32_bf16(qa[qf], db[nf], acc2[qf][nf], 0, 0, 0);
    }

    // ----- masked max over this wave's 32 doc rows -----
    int k0m = ms[rowbase + l15];
    int k1m = ms[rowbase + 16 + l15];
#pragma unroll
    for (int qf = 0; qf < 2; ++qf)
#pragma unroll
        for (int reg = 0; reg < 4; ++reg) {
            float v0 = k0m ? acc2[qf][0][reg] : -INFINITY;
            float v1 = k1m ? acc2[qf][1][reg] : -INFINITY;
            float v = fmaxf(v0, v1);
            v = fmaxf(v, __shfl_xor(v, 1));
            v = fmaxf(v, __shfl_xor(v, 2));
            v = fmaxf(v, __shfl_xor(v, 4));
            v = fmaxf(v, __shfl_xor(v, 8));
            if (l15 == 0) wm[w][qf * 16 + g * 4 + reg] = v;
        }
    __syncthreads();

    // ----- cross-wave max, mean over q -----
    if (tid < 32) {
        float mx = wm[0][tid];
#pragma unroll
        for (int ww = 1; ww < 8; ++ww) mx = fmaxf(mx, wm[ww][tid]);
        mx += __shfl_xor(mx, 1); mx += __shfl_xor(mx, 2);
        mx += __shfl_xor(mx, 4); mx += __shfl_xor(mx, 8);
        mx += __shfl_xor(mx, 16);
        if (tid == 0) out[bd] = mx * (1.f / 32.f);
    }
}

extern "C" void kernel_launch(void* const* d_in, const int* in_sizes, int n_in,
                              void* d_out, int out_size, void* d_ws, size_t ws_size,
                              hipStream_t stream) {
    const float* q_hidden = (const float*)d_in[0];
    const float* d_hidden = (const float*)d_in[1];
    const int*   d_ids    = (const int*)d_in[2];
    const int*   skiplist = (const int*)d_in[3];
    const float* W        = (const float*)d_in[4];
    float* out = (float*)d_out;

    u16* Wb = (u16*)d_ws;                        // 128*768 bf16 = 192 KB
    u16* Qb = (u16*)((char*)d_ws + 256 * 1024);  // 64*32*128 bf16 = 512 KB

    wconv<<<96, 256, 0, stream>>>(W, Wb);
    qproj<<<64, 256, 0, stream>>>(q_hidden, Wb, Qb);
    dscore<<<BD, 512, 0, stream>>>(d_hidden, d_ids, skiplist, Wb, Qb, out);
}